// Round 8
// baseline (313.791 us; speedup 1.0000x reference)
//
#include <hip/hip_runtime.h>

#define NB  8
#define TOQ 2048
#define TIV 2048
#define HD  128

typedef float f32x4 __attribute__((ext_vector_type(4)));
typedef short s16x8 __attribute__((ext_vector_type(8)));
typedef unsigned short ushort8v __attribute__((ext_vector_type(8)));

__device__ __forceinline__ unsigned short f2bf(float f) {   // RNE f32->bf16
    unsigned u = __float_as_uint(f);
    return (unsigned short)((u + 0x7FFFu + ((u >> 16) & 1u)) >> 16);
}
__device__ __forceinline__ float bf2f(unsigned short h) {
    return __uint_as_float(((unsigned)h) << 16);
}

__device__ __forceinline__ void split8(const float4 a, const float4 b,
                                       ushort8v& h, ushort8v& l) {
    const float x[8] = {a.x, a.y, a.z, a.w, b.x, b.y, b.z, b.w};
    #pragma unroll
    for (int j = 0; j < 8; ++j) {
        const unsigned short hi = f2bf(x[j]);
        h[j] = hi;
        l[j] = f2bf(x[j] - bf2f(hi));
    }
}

// ---------------------------------------------------------------------------
// K0: VT[n][h][s] = bf16(V[n][s][h])  (4 MB scratch for PV B-fragments)
// ---------------------------------------------------------------------------
__global__ __launch_bounds__(256) void k0_vt(
    const float* __restrict__ V, unsigned short* __restrict__ VT)
{
    __shared__ unsigned short tile[64][68];
    const int n  = blockIdx.z;
    const int s0 = blockIdx.x * 64;
    const int h0 = blockIdx.y * 64;
    const int t  = threadIdx.x;

    #pragma unroll
    for (int it = 0; it < 4; ++it) {
        const int f = t + it * 256;
        const int r = f >> 4;
        const int c = f & 15;
        const float4 v = *(const float4*)&V[((size_t)(n * TIV + s0 + r)) * HD + h0 + 4 * c];
        tile[4 * c + 0][r] = f2bf(v.x);
        tile[4 * c + 1][r] = f2bf(v.y);
        tile[4 * c + 2][r] = f2bf(v.z);
        tile[4 * c + 3][r] = f2bf(v.w);
    }
    __syncthreads();

    #pragma unroll
    for (int it = 0; it < 2; ++it) {
        const int f  = t + it * 256;
        const int hh = f >> 3;
        const int sc = f & 7;
        ushort8v o;
        #pragma unroll
        for (int j = 0; j < 8; ++j) o[j] = tile[hh][8 * sc + j];
        *(ushort8v*)&VT[((size_t)(n * HD + h0 + hh)) * TIV + s0 + 8 * sc] = o;
    }
}

// ---------------------------------------------------------------------------
// K1: E = mask ? 0 : exp(Q.V^T) via split-bf16 MFMA.  Round-5 epilogue
// (independent scattered M loads — known fast), but E stored as bf16 packed
// into the FIRST HALF of each P-row's f32 slot:  (ushort*)(Pf + R*TIV) [c].
// Write traffic halves (134 -> 67 MB).  No fused rowsum (k2 pays 67 MB).
// ---------------------------------------------------------------------------
__global__ __launch_bounds__(256) void k1_mfma(
    const float* __restrict__ Q, const float* __restrict__ V,
    const int* __restrict__ M, float* __restrict__ Pf)
{
    __shared__ unsigned short qhi[128 * 32], qlo[128 * 32];
    __shared__ unsigned short vhi[128 * 32], vlo[128 * 32];

    const int n    = blockIdx.z;
    const int tt   = blockIdx.y * 128;
    const int ts   = blockIdx.x * 128;
    const int t    = threadIdx.x;
    const int lane = t & 63;
    const int wave = t >> 6;
    const int wr   = wave >> 1;
    const int wc   = wave & 1;
    const int lr   = lane & 15;
    const int kg   = lane >> 4;

    const float* Qb = Q + ((size_t)n * TOQ + tt) * HD;
    const float* Vb = V + ((size_t)n * TIV + ts) * HD;

    f32x4 acc[4][4];
    #pragma unroll
    for (int i = 0; i < 4; ++i)
        #pragma unroll
        for (int j = 0; j < 4; ++j) acc[i][j] = (f32x4)0.f;

    for (int h0 = 0; h0 < HD; h0 += 32) {
        #pragma unroll
        for (int it = 0; it < 2; ++it) {
            const int i   = t + it * 256;
            const int row = i >> 2;
            const int kb  = i & 3;
            const float* qs = Qb + (size_t)row * HD + h0 + kb * 8;
            const float* vs = Vb + (size_t)row * HD + h0 + kb * 8;
            const float4 q0 = *(const float4*)qs, q1 = *(const float4*)(qs + 4);
            const float4 v0 = *(const float4*)vs, v1 = *(const float4*)(vs + 4);
            ushort8v qh, ql, vh, vl;
            split8(q0, q1, qh, ql);
            split8(v0, v1, vh, vl);
            *(ushort8v*)(qhi + i * 8) = qh;
            *(ushort8v*)(qlo + i * 8) = ql;
            *(ushort8v*)(vhi + i * 8) = vh;
            *(ushort8v*)(vlo + i * 8) = vl;
        }
        __syncthreads();

        s16x8 aH[4], aL[4];
        #pragma unroll
        for (int fm = 0; fm < 4; ++fm) {
            const int off = (wr * 64 + fm * 16 + lr) * 32 + kg * 8;
            aH[fm] = *(const s16x8*)(qhi + off);
            aL[fm] = *(const s16x8*)(qlo + off);
        }
        #pragma unroll
        for (int fn = 0; fn < 4; ++fn) {
            const int off = (wc * 64 + fn * 16 + lr) * 32 + kg * 8;
            const s16x8 bH = *(const s16x8*)(vhi + off);
            const s16x8 bL = *(const s16x8*)(vlo + off);
            #pragma unroll
            for (int fm = 0; fm < 4; ++fm) {
                acc[fm][fn] = __builtin_amdgcn_mfma_f32_16x16x32_bf16(aH[fm], bH, acc[fm][fn], 0, 0, 0);
                acc[fm][fn] = __builtin_amdgcn_mfma_f32_16x16x32_bf16(aH[fm], bL, acc[fm][fn], 0, 0, 0);
                acc[fm][fn] = __builtin_amdgcn_mfma_f32_16x16x32_bf16(aL[fm], bH, acc[fm][fn], 0, 0, 0);
            }
        }
        __syncthreads();
    }

    // epilogue: mask + exp, bf16 store into row-half slot (round-5 structure)
    #pragma unroll
    for (int fm = 0; fm < 4; ++fm) {
        #pragma unroll
        for (int fn = 0; fn < 4; ++fn) {
            #pragma unroll
            for (int ri = 0; ri < 4; ++ri) {
                const int r = tt + wr * 64 + fm * 16 + kg * 4 + ri;
                const int c = ts + wc * 64 + fn * 16 + lr;
                const size_t R   = (size_t)n * TOQ + r;
                const size_t off = R * TIV + c;
                unsigned short* Eu = (unsigned short*)(Pf + R * TIV);
                Eu[c] = M[off] ? (unsigned short)0 : f2bf(__expf(acc[fm][fn][ri]));
            }
        }
    }
}

// ---------------------------------------------------------------------------
// K2: rec[row] = 1 / sum_s E[row][s]   (one wave per row, bf16 E: 67 MB)
// ---------------------------------------------------------------------------
__global__ __launch_bounds__(256) void k2_rowsum(
    const float* __restrict__ Pf, float* __restrict__ rec)
{
    const int row = blockIdx.x * 4 + (threadIdx.x >> 6);
    const int l   = threadIdx.x & 63;
    const unsigned short* Eu = (const unsigned short*)(Pf + (size_t)row * TIV);
    float s = 0.f;
    #pragma unroll
    for (int kk = 0; kk < 4; ++kk) {
        const ushort8v v = *(const ushort8v*)&Eu[(l + 64 * kk) * 8];
        #pragma unroll
        for (int j = 0; j < 8; ++j) s += bf2f(v[j]);
    }
    #pragma unroll
    for (int off = 32; off > 0; off >>= 1) s += __shfl_down(s, off, 64);
    if (l == 0) rec[row] = 1.f / s;
}

// ---------------------------------------------------------------------------
// K3: fused normalize + P-writeback + MFMA PV, bf16-E in-place expansion.
// Phase A: each wave register-stages its full E-quarter (16x ushort8).
// __syncthreads. Phase B: scale, write P f32 (overwrites E bytes — safe now),
// cvt bf16, MFMA vs VT.  Epilogue: 4-wave LDS reduction per row group.
// ---------------------------------------------------------------------------
__global__ __launch_bounds__(512, 4) void k3_pv(
    float* __restrict__ Pf, const unsigned short* __restrict__ VT,
    const float* __restrict__ rec, float* __restrict__ O)
{
    __shared__ float red[2][3][16][132];

    const int n    = blockIdx.y;
    const int r0   = blockIdx.x * 32;
    const int t    = threadIdx.x;
    const int wave = t >> 6;
    const int lane = t & 63;
    const int p    = wave >> 2;                  // 0..1 row group
    const int q    = wave & 3;                   // 0..3 k quarter
    const int lr   = lane & 15;
    const int kg   = lane >> 4;

    const int rowg = r0 + p * 16 + lr;
    const float rc = rec[n * TOQ + rowg];
    float* Prow = Pf + ((size_t)n * TOQ + rowg) * TIV;
    const unsigned short* Erow = (const unsigned short*)Prow;
    const unsigned short* VTb  = VT + (size_t)n * HD * TIV;

    // Phase A: stage this wave's E quarter (16 rows handled lane-wise; per
    // lane 16 independent 16B loads = 128 bf16)
    ushort8v est[16];
    #pragma unroll
    for (int i = 0; i < 16; ++i)
        est[i] = *(const ushort8v*)&Erow[q * 512 + i * 32 + kg * 8];

    __syncthreads();                             // all E reads done before P writes

    f32x4 acc[8];
    #pragma unroll
    for (int fn = 0; fn < 8; ++fn) acc[fn] = (f32x4)0.f;

    #pragma unroll 2
    for (int i = 0; i < 16; ++i) {
        const int k = q * 512 + i * 32 + kg * 8;
        const ushort8v ev = est[i];
        float pv[8];
        #pragma unroll
        for (int j = 0; j < 8; ++j) pv[j] = bf2f(ev[j]) * rc;

        float4 p0, p1;
        p0.x = pv[0]; p0.y = pv[1]; p0.z = pv[2]; p0.w = pv[3];
        p1.x = pv[4]; p1.y = pv[5]; p1.z = pv[6]; p1.w = pv[7];
        *(float4*)&Prow[k]     = p0;             // P output (f32)
        *(float4*)&Prow[k + 4] = p1;

        s16x8 a;
        #pragma unroll
        for (int j = 0; j < 8; ++j) a[j] = (short)f2bf(pv[j]);

        #pragma unroll
        for (int fn = 0; fn < 8; ++fn) {
            const s16x8 b = *(const s16x8*)&VTb[(size_t)(fn * 16 + lr) * TIV + k];
            acc[fn] = __builtin_amdgcn_mfma_f32_16x16x32_bf16(a, b, acc[fn], 0, 0, 0);
        }
    }

    // 4-wave reduction per row group: q=1..3 park, q=0 adds + stores
    if (q != 0) {
        #pragma unroll
        for (int fn = 0; fn < 8; ++fn)
            #pragma unroll
            for (int ri = 0; ri < 4; ++ri)
                red[p][q - 1][kg * 4 + ri][fn * 16 + lr] = acc[fn][ri];
    }
    __syncthreads();
    if (q == 0) {
        #pragma unroll
        for (int fn = 0; fn < 8; ++fn) {
            #pragma unroll
            for (int ri = 0; ri < 4; ++ri) {
                const int orow = r0 + p * 16 + kg * 4 + ri;
                float o = acc[fn][ri];
                o += red[p][0][kg * 4 + ri][fn * 16 + lr];
                o += red[p][1][kg * 4 + ri][fn * 16 + lr];
                o += red[p][2][kg * 4 + ri][fn * 16 + lr];
                O[((size_t)n * TOQ + orow) * HD + fn * 16 + lr] = o;
            }
        }
    }
}

// ---------------------------------------------------------------------------
extern "C" void kernel_launch(void* const* d_in, const int* in_sizes, int n_in,
                              void* d_out, int out_size, void* d_ws, size_t ws_size,
                              hipStream_t stream)
{
    const float* Q = (const float*)d_in[0];
    const float* V = (const float*)d_in[1];
    const int*   M = (const int*)d_in[2];

    float* O  = (float*)d_out;                        // [8][2048][128] f32
    float* Pf = O + (size_t)NB * TOQ * HD;            // [8][2048][2048] f32 (P out; E bf16 staged in row-halves)

    float*          recb = (float*)d_ws;                               // 64 KB
    unsigned short* VT   = (unsigned short*)((char*)d_ws + (1 << 16)); // 4 MB

    k0_vt    <<<dim3(TIV / 64, HD / 64, NB), 256, 0, stream>>>(V, VT);
    k1_mfma  <<<dim3(TIV / 128, TOQ / 128, NB), 256, 0, stream>>>(Q, V, M, Pf);
    k2_rowsum<<<dim3(NB * TOQ / 4), 256, 0, stream>>>(Pf, recb);
    k3_pv    <<<dim3(TOQ / 32, NB), 512, 0, stream>>>(Pf, VT, recb, O);
}

// Round 9
// 197.797 us; speedup vs baseline: 1.5864x; 1.5864x over previous
//
#include <hip/hip_runtime.h>

#define NB  8
#define TOQ 2048
#define TIV 2048
#define HD  128

typedef float f32x4 __attribute__((ext_vector_type(4)));
typedef short s16x8 __attribute__((ext_vector_type(8)));
typedef unsigned short ushort8v __attribute__((ext_vector_type(8)));

__device__ __forceinline__ unsigned short f2bf(float f) {   // RNE f32->bf16
    unsigned u = __float_as_uint(f);
    return (unsigned short)((u + 0x7FFFu + ((u >> 16) & 1u)) >> 16);
}
__device__ __forceinline__ float bf2f(unsigned short h) {
    return __uint_as_float(((unsigned)h) << 16);
}

__device__ __forceinline__ void split8(const float4 a, const float4 b,
                                       ushort8v& h, ushort8v& l) {
    const float x[8] = {a.x, a.y, a.z, a.w, b.x, b.y, b.z, b.w};
    #pragma unroll
    for (int j = 0; j < 8; ++j) {
        const unsigned short hi = f2bf(x[j]);
        h[j] = hi;
        l[j] = f2bf(x[j] - bf2f(hi));
    }
}

// ---------------------------------------------------------------------------
// K0: VT[n][h][s] = bf16(V[n][s][h])  (4 MB scratch for PV B-fragments)
// ---------------------------------------------------------------------------
__global__ __launch_bounds__(256) void k0_vt(
    const float* __restrict__ V, unsigned short* __restrict__ VT)
{
    __shared__ unsigned short tile[64][68];
    const int n  = blockIdx.z;
    const int s0 = blockIdx.x * 64;
    const int h0 = blockIdx.y * 64;
    const int t  = threadIdx.x;

    #pragma unroll
    for (int it = 0; it < 4; ++it) {
        const int f = t + it * 256;
        const int r = f >> 4;
        const int c = f & 15;
        const float4 v = *(const float4*)&V[((size_t)(n * TIV + s0 + r)) * HD + h0 + 4 * c];
        tile[4 * c + 0][r] = f2bf(v.x);
        tile[4 * c + 1][r] = f2bf(v.y);
        tile[4 * c + 2][r] = f2bf(v.z);
        tile[4 * c + 3][r] = f2bf(v.w);
    }
    __syncthreads();

    #pragma unroll
    for (int it = 0; it < 2; ++it) {
        const int f  = t + it * 256;
        const int hh = f >> 3;
        const int sc = f & 7;
        ushort8v o;
        #pragma unroll
        for (int j = 0; j < 8; ++j) o[j] = tile[hh][8 * sc + j];
        *(ushort8v*)&VT[((size_t)(n * HD + h0 + hh)) * TIV + s0 + 8 * sc] = o;
    }
}

// ---------------------------------------------------------------------------
// K1: E = mask ? 0 : exp(Q.V^T) via split-bf16 MFMA.
// EXACT round-5 structure: plain epilogue, independent scattered M loads,
// f32 stores. DO NOT add dependencies here — every variant (rowsum fusion,
// ballot preamble, bf16 stores) broke load batching and cost 2-4x.
// ---------------------------------------------------------------------------
__global__ __launch_bounds__(256) void k1_mfma(
    const float* __restrict__ Q, const float* __restrict__ V,
    const int* __restrict__ M, float* __restrict__ E)
{
    __shared__ unsigned short qhi[128 * 32], qlo[128 * 32];
    __shared__ unsigned short vhi[128 * 32], vlo[128 * 32];

    const int n    = blockIdx.z;
    const int tt   = blockIdx.y * 128;
    const int ts   = blockIdx.x * 128;
    const int t    = threadIdx.x;
    const int lane = t & 63;
    const int wave = t >> 6;
    const int wr   = wave >> 1;
    const int wc   = wave & 1;
    const int lr   = lane & 15;
    const int kg   = lane >> 4;

    const float* Qb = Q + ((size_t)n * TOQ + tt) * HD;
    const float* Vb = V + ((size_t)n * TIV + ts) * HD;

    f32x4 acc[4][4];
    #pragma unroll
    for (int i = 0; i < 4; ++i)
        #pragma unroll
        for (int j = 0; j < 4; ++j) acc[i][j] = (f32x4)0.f;

    for (int h0 = 0; h0 < HD; h0 += 32) {
        #pragma unroll
        for (int it = 0; it < 2; ++it) {
            const int i   = t + it * 256;
            const int row = i >> 2;
            const int kb  = i & 3;
            const float* qs = Qb + (size_t)row * HD + h0 + kb * 8;
            const float* vs = Vb + (size_t)row * HD + h0 + kb * 8;
            const float4 q0 = *(const float4*)qs, q1 = *(const float4*)(qs + 4);
            const float4 v0 = *(const float4*)vs, v1 = *(const float4*)(vs + 4);
            ushort8v qh, ql, vh, vl;
            split8(q0, q1, qh, ql);
            split8(v0, v1, vh, vl);
            *(ushort8v*)(qhi + i * 8) = qh;
            *(ushort8v*)(qlo + i * 8) = ql;
            *(ushort8v*)(vhi + i * 8) = vh;
            *(ushort8v*)(vlo + i * 8) = vl;
        }
        __syncthreads();

        s16x8 aH[4], aL[4];
        #pragma unroll
        for (int fm = 0; fm < 4; ++fm) {
            const int off = (wr * 64 + fm * 16 + lr) * 32 + kg * 8;
            aH[fm] = *(const s16x8*)(qhi + off);
            aL[fm] = *(const s16x8*)(qlo + off);
        }
        #pragma unroll
        for (int fn = 0; fn < 4; ++fn) {
            const int off = (wc * 64 + fn * 16 + lr) * 32 + kg * 8;
            const s16x8 bH = *(const s16x8*)(vhi + off);
            const s16x8 bL = *(const s16x8*)(vlo + off);
            #pragma unroll
            for (int fm = 0; fm < 4; ++fm) {
                acc[fm][fn] = __builtin_amdgcn_mfma_f32_16x16x32_bf16(aH[fm], bH, acc[fm][fn], 0, 0, 0);
                acc[fm][fn] = __builtin_amdgcn_mfma_f32_16x16x32_bf16(aH[fm], bL, acc[fm][fn], 0, 0, 0);
                acc[fm][fn] = __builtin_amdgcn_mfma_f32_16x16x32_bf16(aL[fm], bH, acc[fm][fn], 0, 0, 0);
            }
        }
        __syncthreads();
    }

    #pragma unroll
    for (int fm = 0; fm < 4; ++fm) {
        #pragma unroll
        for (int fn = 0; fn < 4; ++fn) {
            #pragma unroll
            for (int ri = 0; ri < 4; ++ri) {
                const int r = tt + wr * 64 + fm * 16 + kg * 4 + ri;
                const int c = ts + wc * 64 + fn * 16 + lr;
                const size_t off = ((size_t)n * TOQ + r) * TIV + c;
                E[off] = M[off] ? 0.f : __expf(acc[fm][fn][ri]);
            }
        }
    }
}

// ---------------------------------------------------------------------------
// K2: rec[row] = 1 / sum_s E[row][s]   (one wave per row, f32 E — round 5)
// ---------------------------------------------------------------------------
__global__ __launch_bounds__(256) void k2_rowsum(
    const float* __restrict__ E, float* __restrict__ rec)
{
    const int row = blockIdx.x * 4 + (threadIdx.x >> 6);
    const int l   = threadIdx.x & 63;
    const float4* Er = (const float4*)(E + (size_t)row * TIV);
    float s = 0.f;
    #pragma unroll
    for (int k = 0; k < 8; ++k) {
        const float4 v = Er[l + 64 * k];
        s += (v.x + v.y) + (v.z + v.w);
    }
    #pragma unroll
    for (int off = 32; off > 0; off >>= 1) s += __shfl_down(s, off, 64);
    if (l == 0) rec[row] = 1.f / s;
}

// ---------------------------------------------------------------------------
// K3: barrier-free fused normalize + P-writeback + MFMA PV (round 6/7,
// verified ~56us). 512 blocks x 8 waves: wave = (row-group p, k-quarter q).
// ---------------------------------------------------------------------------
__global__ __launch_bounds__(512) void k3_pv(
    float* __restrict__ EP, const unsigned short* __restrict__ VT,
    const float* __restrict__ rec, float* __restrict__ O)
{
    __shared__ float red[2][3][16][132];

    const int n    = blockIdx.y;
    const int r0   = blockIdx.x * 32;
    const int t    = threadIdx.x;
    const int wave = t >> 6;
    const int lane = t & 63;
    const int p    = wave >> 2;
    const int q    = wave & 3;
    const int lr   = lane & 15;
    const int kg   = lane >> 4;

    const int rowg = r0 + p * 16 + lr;
    const float rc = rec[n * TOQ + rowg];
    float* Erow = EP + ((size_t)n * TOQ + rowg) * TIV;
    const unsigned short* VTb = VT + (size_t)n * HD * TIV;

    f32x4 acc[8];
    #pragma unroll
    for (int fn = 0; fn < 8; ++fn) acc[fn] = (f32x4)0.f;

    const int kbase = q * 512 + kg * 8;

    #pragma unroll 2
    for (int k0 = 0; k0 < 512; k0 += 32) {
        const int k = kbase + k0;
        const float4 e0 = *(const float4*)&Erow[k];
        const float4 e1 = *(const float4*)&Erow[k + 4];
        float4 p0, p1;
        p0.x = e0.x * rc; p0.y = e0.y * rc; p0.z = e0.z * rc; p0.w = e0.w * rc;
        p1.x = e1.x * rc; p1.y = e1.y * rc; p1.z = e1.z * rc; p1.w = e1.w * rc;
        *(float4*)&Erow[k]     = p0;             // P output (f32)
        *(float4*)&Erow[k + 4] = p1;

        s16x8 a;
        a[0] = (short)f2bf(p0.x); a[1] = (short)f2bf(p0.y);
        a[2] = (short)f2bf(p0.z); a[3] = (short)f2bf(p0.w);
        a[4] = (short)f2bf(p1.x); a[5] = (short)f2bf(p1.y);
        a[6] = (short)f2bf(p1.z); a[7] = (short)f2bf(p1.w);

        #pragma unroll
        for (int fn = 0; fn < 8; ++fn) {
            const s16x8 b = *(const s16x8*)&VTb[(size_t)(fn * 16 + lr) * TIV + k];
            acc[fn] = __builtin_amdgcn_mfma_f32_16x16x32_bf16(a, b, acc[fn], 0, 0, 0);
        }
    }

    if (q != 0) {
        #pragma unroll
        for (int fn = 0; fn < 8; ++fn)
            #pragma unroll
            for (int ri = 0; ri < 4; ++ri)
                red[p][q - 1][kg * 4 + ri][fn * 16 + lr] = acc[fn][ri];
    }
    __syncthreads();
    if (q == 0) {
        #pragma unroll
        for (int fn = 0; fn < 8; ++fn) {
            #pragma unroll
            for (int ri = 0; ri < 4; ++ri) {
                const int orow = r0 + p * 16 + kg * 4 + ri;
                float o = acc[fn][ri];
                o += red[p][0][kg * 4 + ri][fn * 16 + lr];
                o += red[p][1][kg * 4 + ri][fn * 16 + lr];
                o += red[p][2][kg * 4 + ri][fn * 16 + lr];
                O[((size_t)n * TOQ + orow) * HD + fn * 16 + lr] = o;
            }
        }
    }
}

// ---------------------------------------------------------------------------
extern "C" void kernel_launch(void* const* d_in, const int* in_sizes, int n_in,
                              void* d_out, int out_size, void* d_ws, size_t ws_size,
                              hipStream_t stream)
{
    const float* Q = (const float*)d_in[0];
    const float* V = (const float*)d_in[1];
    const int*   M = (const int*)d_in[2];

    float* O = (float*)d_out;                         // [8][2048][128] f32
    float* E = O + (size_t)NB * TOQ * HD;             // [8][2048][2048] f32 (P out)

    float*          recb = (float*)d_ws;                               // 64 KB
    unsigned short* VT   = (unsigned short*)((char*)d_ws + (1 << 16)); // 4 MB

    k0_vt    <<<dim3(TIV / 64, HD / 64, NB), 256, 0, stream>>>(V, VT);
    k1_mfma  <<<dim3(TIV / 128, TOQ / 128, NB), 256, 0, stream>>>(Q, V, M, E);
    k2_rowsum<<<dim3(NB * TOQ / 4), 256, 0, stream>>>(E, recb);
    k3_pv    <<<dim3(TOQ / 32, NB), 512, 0, stream>>>(E, VT, recb, O);
}

// Round 10
// 184.203 us; speedup vs baseline: 1.7035x; 1.0738x over previous
//
#include <hip/hip_runtime.h>

#define NB  8
#define TOQ 2048
#define TIV 2048
#define HD  128

typedef float f32x4 __attribute__((ext_vector_type(4)));
typedef short s16x8 __attribute__((ext_vector_type(8)));
typedef unsigned short ushort8v __attribute__((ext_vector_type(8)));

__device__ __forceinline__ unsigned short f2bf(float f) {   // RNE f32->bf16
    unsigned u = __float_as_uint(f);
    return (unsigned short)((u + 0x7FFFu + ((u >> 16) & 1u)) >> 16);
}
__device__ __forceinline__ float bf2f(unsigned short h) {
    return __uint_as_float(((unsigned)h) << 16);
}

__device__ __forceinline__ void split8(const float4 a, const float4 b,
                                       ushort8v& h, ushort8v& l) {
    const float x[8] = {a.x, a.y, a.z, a.w, b.x, b.y, b.z, b.w};
    #pragma unroll
    for (int j = 0; j < 8; ++j) {
        const unsigned short hi = f2bf(x[j]);
        h[j] = hi;
        l[j] = f2bf(x[j] - bf2f(hi));
    }
}

// ---------------------------------------------------------------------------
// K0: VT[n][h][s] = bf16(V[n][s][h])  (4 MB scratch for PV B-fragments)
// ---------------------------------------------------------------------------
__global__ __launch_bounds__(256) void k0_vt(
    const float* __restrict__ V, unsigned short* __restrict__ VT)
{
    __shared__ unsigned short tile[64][68];
    const int n  = blockIdx.z;
    const int s0 = blockIdx.x * 64;
    const int h0 = blockIdx.y * 64;
    const int t  = threadIdx.x;

    #pragma unroll
    for (int it = 0; it < 4; ++it) {
        const int f = t + it * 256;
        const int r = f >> 4;
        const int c = f & 15;
        const float4 v = *(const float4*)&V[((size_t)(n * TIV + s0 + r)) * HD + h0 + 4 * c];
        tile[4 * c + 0][r] = f2bf(v.x);
        tile[4 * c + 1][r] = f2bf(v.y);
        tile[4 * c + 2][r] = f2bf(v.z);
        tile[4 * c + 3][r] = f2bf(v.w);
    }
    __syncthreads();

    #pragma unroll
    for (int it = 0; it < 2; ++it) {
        const int f  = t + it * 256;
        const int hh = f >> 3;
        const int sc = f & 7;
        ushort8v o;
        #pragma unroll
        for (int j = 0; j < 8; ++j) o[j] = tile[hh][8 * sc + j];
        *(ushort8v*)&VT[((size_t)(n * HD + h0 + hh)) * TIV + s0 + 8 * sc] = o;
    }
}

// ---------------------------------------------------------------------------
// K1: E = mask ? 0 : exp(Q.V^T), computed TRANSPOSED (A=V-tile, B=Q-tile) so
// each lane's C/D fragment holds 4 CONSECUTIVE ti for one to-row:
//   - mask loads become int4 (16B), E stores become float4 (16B)
//   - fused row-sum needs only 2 shfl_xor (over kg) + 1 partial store
// Staging/main loop identical to the verified kernel; only fragment-read
// roles and the epilogue indexing change.
// ---------------------------------------------------------------------------
__global__ __launch_bounds__(256) void k1_mfma(
    const float* __restrict__ Q, const float* __restrict__ V,
    const int* __restrict__ M, float* __restrict__ E,
    float* __restrict__ part)
{
    __shared__ unsigned short qhi[128 * 32], qlo[128 * 32];
    __shared__ unsigned short vhi[128 * 32], vlo[128 * 32];

    const int n    = blockIdx.z;
    const int tt   = blockIdx.y * 128;   // to-rows (Q side)
    const int ts   = blockIdx.x * 128;   // ti-cols (V side)
    const int t    = threadIdx.x;
    const int lane = t & 63;
    const int wave = t >> 6;
    const int wr   = wave >> 1;          // V-side (ti) half
    const int wc   = wave & 1;           // Q-side (to) half
    const int lr   = lane & 15;
    const int kg   = lane >> 4;

    const float* Qb = Q + ((size_t)n * TOQ + tt) * HD;
    const float* Vb = V + ((size_t)n * TIV + ts) * HD;

    f32x4 acc[4][4];                     // [fm: ti-tile][fn: to-tile]
    #pragma unroll
    for (int i = 0; i < 4; ++i)
        #pragma unroll
        for (int j = 0; j < 4; ++j) acc[i][j] = (f32x4)0.f;

    for (int h0 = 0; h0 < HD; h0 += 32) {
        #pragma unroll
        for (int it = 0; it < 2; ++it) {
            const int i   = t + it * 256;
            const int row = i >> 2;
            const int kb  = i & 3;
            const float* qs = Qb + (size_t)row * HD + h0 + kb * 8;
            const float* vs = Vb + (size_t)row * HD + h0 + kb * 8;
            const float4 q0 = *(const float4*)qs, q1 = *(const float4*)(qs + 4);
            const float4 v0 = *(const float4*)vs, v1 = *(const float4*)(vs + 4);
            ushort8v qh, ql, vh, vl;
            split8(q0, q1, qh, ql);
            split8(v0, v1, vh, vl);
            *(ushort8v*)(qhi + i * 8) = qh;
            *(ushort8v*)(qlo + i * 8) = ql;
            *(ushort8v*)(vhi + i * 8) = vh;
            *(ushort8v*)(vlo + i * 8) = vl;
        }
        __syncthreads();

        // A <- V fragments (ti side), B <- Q fragments (to side)
        s16x8 aH[4], aL[4];
        #pragma unroll
        for (int fm = 0; fm < 4; ++fm) {
            const int off = (wr * 64 + fm * 16 + lr) * 32 + kg * 8;
            aH[fm] = *(const s16x8*)(vhi + off);
            aL[fm] = *(const s16x8*)(vlo + off);
        }
        #pragma unroll
        for (int fn = 0; fn < 4; ++fn) {
            const int off = (wc * 64 + fn * 16 + lr) * 32 + kg * 8;
            const s16x8 bH = *(const s16x8*)(qhi + off);
            const s16x8 bL = *(const s16x8*)(qlo + off);
            #pragma unroll
            for (int fm = 0; fm < 4; ++fm) {
                acc[fm][fn] = __builtin_amdgcn_mfma_f32_16x16x32_bf16(aH[fm], bH, acc[fm][fn], 0, 0, 0);
                acc[fm][fn] = __builtin_amdgcn_mfma_f32_16x16x32_bf16(aH[fm], bL, acc[fm][fn], 0, 0, 0);
                acc[fm][fn] = __builtin_amdgcn_mfma_f32_16x16x32_bf16(aL[fm], bH, acc[fm][fn], 0, 0, 0);
            }
        }
        __syncthreads();
    }

    // epilogue: D[row = ti-local (kg*4+ri)][col = to-local (lr)]
    // -> lane owns 4 consecutive ti per (fm,fn): int4 mask, float4 store.
    #pragma unroll
    for (int fn = 0; fn < 4; ++fn) {
        const int to_g = tt + wc * 64 + fn * 16 + lr;
        const size_t rowbase = ((size_t)n * TOQ + to_g) * TIV;
        float rs = 0.f;
        #pragma unroll
        for (int fm = 0; fm < 4; ++fm) {
            const int ti_g = ts + wr * 64 + fm * 16 + kg * 4;
            const int4 mv = *(const int4*)&M[rowbase + ti_g];
            float4 e;
            e.x = mv.x ? 0.f : __expf(acc[fm][fn][0]);
            e.y = mv.y ? 0.f : __expf(acc[fm][fn][1]);
            e.z = mv.z ? 0.f : __expf(acc[fm][fn][2]);
            e.w = mv.w ? 0.f : __expf(acc[fm][fn][3]);
            *(float4*)&E[rowbase + ti_g] = e;
            rs += (e.x + e.y) + (e.z + e.w);
        }
        // sum over kg lanes (ti halves within this wave's 64-col half)
        rs += __shfl_xor(rs, 16, 64);
        rs += __shfl_xor(rs, 32, 64);
        if (kg == 0)
            part[((size_t)n * TOQ + to_g) * 32 + blockIdx.x * 2 + wr] = rs;
    }
}

// ---------------------------------------------------------------------------
// K2: rec[row] = 1 / sum of 32 partials   (one thread per row, 2 MB total)
// ---------------------------------------------------------------------------
__global__ __launch_bounds__(256) void k2_rowsum(
    const float* __restrict__ part, float* __restrict__ rec)
{
    const int row = blockIdx.x * 256 + threadIdx.x;
    const float4* p4 = (const float4*)(part + (size_t)row * 32);
    float s = 0.f;
    #pragma unroll
    for (int i = 0; i < 8; ++i) {
        const float4 v = p4[i];
        s += (v.x + v.y) + (v.z + v.w);
    }
    rec[row] = 1.f / s;
}

// ---------------------------------------------------------------------------
// K3: barrier-free fused normalize + P-writeback + MFMA PV (verified ~56us).
// 512 blocks x 8 waves: wave = (row-group p, k-quarter q). Same-dtype
// in-place E->P rewrite keeps per-cell RAW within a lane (race-free).
// ---------------------------------------------------------------------------
__global__ __launch_bounds__(512) void k3_pv(
    float* __restrict__ EP, const unsigned short* __restrict__ VT,
    const float* __restrict__ rec, float* __restrict__ O)
{
    __shared__ float red[2][3][16][132];

    const int n    = blockIdx.y;
    const int r0   = blockIdx.x * 32;
    const int t    = threadIdx.x;
    const int wave = t >> 6;
    const int lane = t & 63;
    const int p    = wave >> 2;
    const int q    = wave & 3;
    const int lr   = lane & 15;
    const int kg   = lane >> 4;

    const int rowg = r0 + p * 16 + lr;
    const float rc = rec[n * TOQ + rowg];
    float* Erow = EP + ((size_t)n * TOQ + rowg) * TIV;
    const unsigned short* VTb = VT + (size_t)n * HD * TIV;

    f32x4 acc[8];
    #pragma unroll
    for (int fn = 0; fn < 8; ++fn) acc[fn] = (f32x4)0.f;

    const int kbase = q * 512 + kg * 8;

    #pragma unroll 2
    for (int k0 = 0; k0 < 512; k0 += 32) {
        const int k = kbase + k0;
        const float4 e0 = *(const float4*)&Erow[k];
        const float4 e1 = *(const float4*)&Erow[k + 4];
        float4 p0, p1;
        p0.x = e0.x * rc; p0.y = e0.y * rc; p0.z = e0.z * rc; p0.w = e0.w * rc;
        p1.x = e1.x * rc; p1.y = e1.y * rc; p1.z = e1.z * rc; p1.w = e1.w * rc;
        *(float4*)&Erow[k]     = p0;             // P output (f32)
        *(float4*)&Erow[k + 4] = p1;

        s16x8 a;
        a[0] = (short)f2bf(p0.x); a[1] = (short)f2bf(p0.y);
        a[2] = (short)f2bf(p0.z); a[3] = (short)f2bf(p0.w);
        a[4] = (short)f2bf(p1.x); a[5] = (short)f2bf(p1.y);
        a[6] = (short)f2bf(p1.z); a[7] = (short)f2bf(p1.w);

        #pragma unroll
        for (int fn = 0; fn < 8; ++fn) {
            const s16x8 b = *(const s16x8*)&VTb[(size_t)(fn * 16 + lr) * TIV + k];
            acc[fn] = __builtin_amdgcn_mfma_f32_16x16x32_bf16(a, b, acc[fn], 0, 0, 0);
        }
    }

    if (q != 0) {
        #pragma unroll
        for (int fn = 0; fn < 8; ++fn)
            #pragma unroll
            for (int ri = 0; ri < 4; ++ri)
                red[p][q - 1][kg * 4 + ri][fn * 16 + lr] = acc[fn][ri];
    }
    __syncthreads();
    if (q == 0) {
        #pragma unroll
        for (int fn = 0; fn < 8; ++fn) {
            #pragma unroll
            for (int ri = 0; ri < 4; ++ri) {
                const int orow = r0 + p * 16 + kg * 4 + ri;
                float o = acc[fn][ri];
                o += red[p][0][kg * 4 + ri][fn * 16 + lr];
                o += red[p][1][kg * 4 + ri][fn * 16 + lr];
                o += red[p][2][kg * 4 + ri][fn * 16 + lr];
                O[((size_t)n * TOQ + orow) * HD + fn * 16 + lr] = o;
            }
        }
    }
}

// ---------------------------------------------------------------------------
extern "C" void kernel_launch(void* const* d_in, const int* in_sizes, int n_in,
                              void* d_out, int out_size, void* d_ws, size_t ws_size,
                              hipStream_t stream)
{
    const float* Q = (const float*)d_in[0];
    const float* V = (const float*)d_in[1];
    const int*   M = (const int*)d_in[2];

    float* O = (float*)d_out;                         // [8][2048][128] f32
    float* E = O + (size_t)NB * TOQ * HD;             // [8][2048][2048] f32 (P out)

    float*          recb = (float*)d_ws;                                   // 64 KB
    float*          part = (float*)((char*)d_ws + (1 << 16));              // 2 MB
    unsigned short* VT   = (unsigned short*)((char*)d_ws + (1 << 16) + (NB * TOQ * 32 * 4)); // 4 MB

    k0_vt    <<<dim3(TIV / 64, HD / 64, NB), 256, 0, stream>>>(V, VT);
    k1_mfma  <<<dim3(TIV / 128, TOQ / 128, NB), 256, 0, stream>>>(Q, V, M, E, part);
    k2_rowsum<<<dim3(NB * TOQ / 256), 256, 0, stream>>>(part, recb);
    k3_pv    <<<dim3(TOQ / 32, NB), 512, 0, stream>>>(E, VT, recb, O);
}